// Round 9
// baseline (274.184 us; speedup 1.0000x reference)
//
#include <hip/hip_runtime.h>

typedef __attribute__((ext_vector_type(8))) short short8v;
typedef __attribute__((ext_vector_type(4))) float f32x4;

// ---------- helpers ----------
__device__ inline unsigned short f2b(float f) {
    unsigned u = __builtin_bit_cast(unsigned, f);
    unsigned r = u + 0x7fffu + ((u >> 16) & 1u);
    return (unsigned short)(r >> 16);
}
__device__ inline void gload16(const void* g, void* l) {
    __builtin_amdgcn_global_load_lds(
        (const __attribute__((address_space(1))) void*)g,
        (__attribute__((address_space(3))) void*)l, 16, 0, 0);
}

// device-scope grid barrier (all 512 blocks guaranteed co-resident:
// LDS 50432B -> 3 blocks/CU, launch_bounds(256,2) -> VGPR<=256 -> 2 blocks/CU,
// 2 x 256 CU = 512). AGENT-scope acq/rel handles cross-XCD visibility.
__device__ __forceinline__ void gsync(int* cnt, int* gen) {
    __syncthreads();
    if (threadIdx.x == 0) {
        int g = __hip_atomic_load(gen, __ATOMIC_ACQUIRE, __HIP_MEMORY_SCOPE_AGENT);
        __threadfence();
        int a = __hip_atomic_fetch_add(cnt, 1, __ATOMIC_ACQ_REL, __HIP_MEMORY_SCOPE_AGENT);
        if (a == (int)gridDim.x - 1) {
            __hip_atomic_store(cnt, 0, __ATOMIC_RELAXED, __HIP_MEMORY_SCOPE_AGENT);
            __hip_atomic_fetch_add(gen, 1, __ATOMIC_RELEASE, __HIP_MEMORY_SCOPE_AGENT);
        } else {
            while (__hip_atomic_load(gen, __ATOMIC_ACQUIRE, __HIP_MEMORY_SCOPE_AGENT) == g)
                __builtin_amdgcn_s_sleep(2);
        }
    }
    __syncthreads();
}

__global__ __launch_bounds__(256, 2)
void fused_kernel(const float* __restrict__ x, const float* __restrict__ wkv,
                  const float* __restrict__ wq, const float* __restrict__ wp,
                  const float* __restrict__ buf, const int* __restrict__ sl,
                  const float* __restrict__ bkv, const float* __restrict__ bq,
                  const float* __restrict__ bp,
                  short* __restrict__ xb, short* __restrict__ wkvqb,
                  short* __restrict__ wpb, short* __restrict__ qbuf,
                  short* __restrict__ extb, short* __restrict__ ob,
                  int* __restrict__ extrow, int* __restrict__ destrow,
                  float* __restrict__ biascat, float* __restrict__ y,
                  int* bar_cnt, int* bar_gen,
                  long n0, long n1, long n2, long n3, long n4,
                  int T, int Bn, int MAXL, int EK, int NKVQ)
{
    __shared__ __align__(16) char pool[50432];
    const int tid = threadIdx.x;
    const int lane = tid & 63, wid = tid >> 6;
    const int nlo = lane & 15, g4 = lane >> 4;

    // ================= phase 0: prep + padzero =================
    {
        long gs = (long)gridDim.x * blockDim.x;
        long gid0 = (long)blockIdx.x * blockDim.x + tid;
        for (long e = gid0 * 8; e < n4; e += gs * 8) {
            if (e < n3) {
                const float* s; long off;
                if (e < n0)      { s = x;   off = e; }
                else if (e < n1) { s = wkv; off = e - n0; }
                else if (e < n2) { s = wq;  off = e - n1; }
                else             { s = wp;  off = e - n2; }
                float4 a = *(const float4*)(s + off);
                float4 b = *(const float4*)(s + off + 4);
                short8v o;
                o[0] = (short)f2b(a.x); o[1] = (short)f2b(a.y);
                o[2] = (short)f2b(a.z); o[3] = (short)f2b(a.w);
                o[4] = (short)f2b(b.x); o[5] = (short)f2b(b.y);
                o[6] = (short)f2b(b.z); o[7] = (short)f2b(b.w);
                *(short8v*)(xb + e) = o;
            } else {
                long off = e - n3;
                int brow = (int)(off / EK);
                int bcol = (int)(off % EK);
                float4 a = *(const float4*)(buf + off);
                float4 b = *(const float4*)(buf + off + 4);
                short8v o;
                o[0] = (short)f2b(a.x); o[1] = (short)f2b(a.y);
                o[2] = (short)f2b(a.z); o[3] = (short)f2b(a.w);
                o[4] = (short)f2b(b.x); o[5] = (short)f2b(b.y);
                o[6] = (short)f2b(b.z); o[7] = (short)f2b(b.w);
                int start = 0;
                for (int s8 = 0; s8 < Bn; ++s8) {
                    int dr = 31 * s8 + start + brow;
                    *(short8v*)&extb[(size_t)dr * EK + bcol] = o;
                    start += sl[s8];
                }
            }
        }
        if (gid0 < T) {
            int start = 0, seg = 0, jloc = 0;
            for (int i = 0; i < Bn; ++i) {
                int len = sl[i];
                if (gid0 >= start && gid0 < start + len) { seg = i; jloc = (int)gid0 - start; }
                start += len;
            }
            destrow[gid0] = seg * MAXL + jloc;
            extrow[gid0]  = 31 * (seg + 1) + (int)gid0;
        }
        if (gid0 < NKVQ)
            biascat[gid0] = (gid0 < EK) ? bkv[gid0] : bq[gid0 - EK];
        // padzero: one y row per block-iteration
        for (int row = blockIdx.x; row < Bn * MAXL; row += gridDim.x) {
            int seg = row / MAXL, pos = row - seg * MAXL;
            if (pos >= sl[seg]) {
                float4 z = {0.f, 0.f, 0.f, 0.f};
                *(float4*)&y[(size_t)row * 1024 + tid * 4] = z;
            }
        }
    }
    gsync(bar_cnt, bar_gen);

    // ================= phase 1: gemm1  [T,1024]@[2048,1024]^T =================
    {
        short* lA = (short*)pool;              // [2][128*32]
        short* lB = (short*)(pool + 16384);    // [2][128*32]
        int bid = (blockIdx.x & 7) * 64 + (blockIdx.x >> 3);
        int m0 = (bid >> 4) << 7, nn0 = (bid & 15) << 7;
        int wm = wid >> 1, wn = wid & 1;
        f32x4 acc[4][4];
        #pragma unroll
        for (int i = 0; i < 4; ++i)
            #pragma unroll
            for (int j2 = 0; j2 < 4; ++j2)
                acc[i][j2] = (f32x4)(0.f);
        int srow = tid >> 2, scol = (tid & 3) * 8;
        const short* ga = xb + (size_t)(m0 + srow) * 1024 + scol;
        const short* gb = wkvqb + (size_t)(nn0 + srow) * 1024 + scol;
        auto stage1 = [&](int b2, int k0) {
            gload16(ga + k0,           &lA[b2 * 4096 + tid * 8]);
            gload16(ga + 65536 + k0,   &lA[b2 * 4096 + 2048 + tid * 8]);
            gload16(gb + k0,           &lB[b2 * 4096 + tid * 8]);
            gload16(gb + 65536 + k0,   &lB[b2 * 4096 + 2048 + tid * 8]);
        };
        stage1(0, 0);
        for (int t = 0; t < 32; ++t) {
            __syncthreads();
            if (t + 1 < 32) stage1((t + 1) & 1, (t + 1) << 5);
            int cb = t & 1;
            short8v af[4], bf[4];
            #pragma unroll
            for (int f = 0; f < 4; ++f)
                af[f] = *(const short8v*)&lA[cb * 4096 + (wm * 64 + f * 16 + nlo) * 32 + g4 * 8];
            #pragma unroll
            for (int f = 0; f < 4; ++f)
                bf[f] = *(const short8v*)&lB[cb * 4096 + (wn * 64 + f * 16 + nlo) * 32 + g4 * 8];
            #pragma unroll
            for (int i = 0; i < 4; ++i)
                #pragma unroll
                for (int j2 = 0; j2 < 4; ++j2)
                    acc[i][j2] = __builtin_amdgcn_mfma_f32_16x16x32_bf16(
                        af[i], bf[j2], acc[i][j2], 0, 0, 0);
        }
        int cr = g4 * 4;
        float bv[4];
        #pragma unroll
        for (int j2 = 0; j2 < 4; ++j2)
            bv[j2] = biascat[nn0 + wn * 64 + j2 * 16 + nlo];
        #pragma unroll
        for (int i = 0; i < 4; ++i) {
            #pragma unroll
            for (int rr = 0; rr < 4; ++rr) {
                int row = m0 + wm * 64 + i * 16 + cr + rr;
                int dr = extrow[row];
                #pragma unroll
                for (int j2 = 0; j2 < 4; ++j2) {
                    int col = nn0 + wn * 64 + j2 * 16 + nlo;
                    float v = acc[i][j2][rr] + bv[j2];
                    if (col < 1536)
                        extb[(size_t)dr * 1536 + col] = (short)f2b(v);
                    else
                        qbuf[(size_t)row * 512 + (col - 1536)] = (short)f2b(v);
                }
            }
        }
    }
    gsync(bar_cnt, bar_gen);

    // ================= phase 2: attention (2 tiles per block) =================
    {
        short* lK = (short*)pool;               // 4*48*40
        short* lV = (short*)(pool + 15360);     // 4*48*66
        short* ps = (short*)(pool + 40704);     // 4*16*76
        int sb = (blockIdx.x & 7) * 64 + (blockIdx.x >> 3);
        // zero ps cols 48..63 once (never rewritten)
        if (tid < 128) {
            int hd = tid >> 5, rw = (tid >> 1) & 15, hf = tid & 1;
            uint4 z = {0u, 0u, 0u, 0u};
            *(uint4*)&ps[hd * 1216 + rw * 76 + 48 + hf * 8] = z;
        }
        #pragma unroll 1
        for (int it = 0; it < 2; ++it) {
            int tile = sb * 2 + it;
            int tg = tile >> 2, hg = tile & 3;
            int t0 = tg << 4, h0 = hg << 2;
            int r0 = extrow[t0] - 31;
            if (it) __syncthreads();   // prev PV reads done before restaging
            #pragma unroll
            for (int p = 0; p < 3; ++p) {
                int q = p * 256 + tid;
                int hd = q / 192, rem = q - hd * 192;
                int rr = rem >> 2, cc = rem & 3;
                int sr = r0 + (rr < 47 ? rr : 46);
                *(short8v*)&lK[hd * 1920 + rr * 40 + cc * 8] =
                    *(const short8v*)&extb[(size_t)sr * 1536 + (h0 + hd) * 32 + cc * 8];
            }
            #pragma unroll
            for (int p = 0; p < 6; ++p) {
                int q = p * 256 + tid;
                int hd = q / 384, rem = q - hd * 384;
                int rr = rem >> 3, cc = rem & 7;
                int sr = r0 + (rr < 47 ? rr : 46);
                *(short8v*)&lV[hd * 3168 + rr * 66 + cc * 8] =
                    *(const short8v*)&extb[(size_t)sr * 1536 + 512 + (h0 + hd) * 64 + cc * 8];
            }
            int h = h0 + wid;
            short8v aq = *(const short8v*)&qbuf[(size_t)(t0 + nlo) * 512 + h * 32 + g4 * 8];
            __syncthreads();
            f32x4 sg[3];
            #pragma unroll
            for (int g = 0; g < 3; ++g) {
                short8v bk = *(const short8v*)&lK[wid * 1920 + (g * 16 + nlo) * 40 + g4 * 8];
                f32x4 z = (f32x4)(0.f);
                sg[g] = __builtin_amdgcn_mfma_f32_16x16x32_bf16(aq, bk, z, 0, 0, 0);
            }
            const float scale = 0.17677669529663687f;
            #pragma unroll
            for (int r = 0; r < 4; ++r) {
                int tk = g4 * 4 + r;
                bool v0 = (nlo >= tk);
                bool v2 = (nlo < tk);
                float s0 = v0 ? sg[0][r] * scale : -1e30f;
                float s1 = sg[1][r] * scale;
                float s2 = v2 ? sg[2][r] * scale : -1e30f;
                float m = fmaxf(fmaxf(s0, s1), s2);
                m = fmaxf(m, __shfl_xor(m, 1, 64));
                m = fmaxf(m, __shfl_xor(m, 2, 64));
                m = fmaxf(m, __shfl_xor(m, 4, 64));
                m = fmaxf(m, __shfl_xor(m, 8, 64));
                float p0 = v0 ? __expf(s0 - m) : 0.f;
                float p1 = __expf(s1 - m);
                float p2 = v2 ? __expf(s2 - m) : 0.f;
                float sm = p0 + p1 + p2;
                sm += __shfl_xor(sm, 1, 64);
                sm += __shfl_xor(sm, 2, 64);
                sm += __shfl_xor(sm, 4, 64);
                sm += __shfl_xor(sm, 8, 64);
                float inv = 1.f / sm;
                short* pr = &ps[wid * 1216 + tk * 76];
                pr[nlo]      = (short)f2b(p0 * inv);
                pr[16 + nlo] = (short)f2b(p1 * inv);
                pr[32 + nlo] = (short)f2b(p2 * inv);
            }
            short8v pa0 = *(const short8v*)&ps[wid * 1216 + nlo * 76 + g4 * 8];
            short8v pa1 = *(const short8v*)&ps[wid * 1216 + nlo * 76 + 32 + g4 * 8];
            #pragma unroll
            for (int dvt = 0; dvt < 4; ++dvt) {
                f32x4 acc = (f32x4)(0.f);
                short8v b0, b1;
                #pragma unroll
                for (int j = 0; j < 8; ++j)
                    b0[j] = lV[wid * 3168 + (g4 * 8 + j) * 66 + dvt * 16 + nlo];
                acc = __builtin_amdgcn_mfma_f32_16x16x32_bf16(pa0, b0, acc, 0, 0, 0);
                #pragma unroll
                for (int j = 0; j < 8; ++j) {
                    int lr = 32 + g4 * 8 + j;
                    int rowc = lr < 47 ? lr : 47;
                    b1[j] = lV[wid * 3168 + rowc * 66 + dvt * 16 + nlo];
                }
                acc = __builtin_amdgcn_mfma_f32_16x16x32_bf16(pa1, b1, acc, 0, 0, 0);
                #pragma unroll
                for (int r = 0; r < 4; ++r) {
                    int t = t0 + g4 * 4 + r;
                    ob[(size_t)t * 1024 + h * 64 + dvt * 16 + nlo] = (short)f2b(acc[r]);
                }
            }
        }
    }
    gsync(bar_cnt, bar_gen);

    // ================= phase 3: gemm2  64x128 tiles, [T,1024]@[1024,1024]^T ====
    {
        short* lA = (short*)pool;              // [2][64*32]
        short* lB = (short*)(pool + 8192);     // [2][128*32]
        int bid = (blockIdx.x & 7) * 64 + (blockIdx.x >> 3);
        int m0 = (bid >> 3) * 64, nn0 = (bid & 7) << 7;
        int wm = wid >> 1, wn = wid & 1;
        f32x4 acc[2][4];
        #pragma unroll
        for (int i = 0; i < 2; ++i)
            #pragma unroll
            for (int j2 = 0; j2 < 4; ++j2)
                acc[i][j2] = (f32x4)(0.f);
        int srow = tid >> 2, scol = (tid & 3) * 8;
        const short* ga = ob + (size_t)(m0 + srow) * 1024 + scol;
        const short* gb = wpb + (size_t)(nn0 + srow) * 1024 + scol;
        auto stage2 = [&](int b2, int k0) {
            if (srow < 64)
                gload16(ga + k0, &lA[b2 * 2048 + tid * 8]);
            gload16(gb + k0,         &lB[b2 * 4096 + tid * 8]);
            gload16(gb + 65536 + k0, &lB[b2 * 4096 + 2048 + tid * 8]);
        };
        stage2(0, 0);
        for (int t = 0; t < 32; ++t) {
            __syncthreads();
            if (t + 1 < 32) stage2((t + 1) & 1, (t + 1) << 5);
            int cb = t & 1;
            short8v af[2], bf[4];
            #pragma unroll
            for (int f = 0; f < 2; ++f)
                af[f] = *(const short8v*)&lA[cb * 2048 + (wm * 32 + f * 16 + nlo) * 32 + g4 * 8];
            #pragma unroll
            for (int f = 0; f < 4; ++f)
                bf[f] = *(const short8v*)&lB[cb * 4096 + (wn * 64 + f * 16 + nlo) * 32 + g4 * 8];
            #pragma unroll
            for (int i = 0; i < 2; ++i)
                #pragma unroll
                for (int j2 = 0; j2 < 4; ++j2)
                    acc[i][j2] = __builtin_amdgcn_mfma_f32_16x16x32_bf16(
                        af[i], bf[j2], acc[i][j2], 0, 0, 0);
        }
        int cr = g4 * 4;
        float bv[4];
        #pragma unroll
        for (int j2 = 0; j2 < 4; ++j2)
            bv[j2] = bp[nn0 + wn * 64 + j2 * 16 + nlo];
        #pragma unroll
        for (int i = 0; i < 2; ++i) {
            #pragma unroll
            for (int rr = 0; rr < 4; ++rr) {
                int row = m0 + wm * 32 + i * 16 + cr + rr;
                int dr = destrow[row];
                #pragma unroll
                for (int j2 = 0; j2 < 4; ++j2) {
                    int col = nn0 + wn * 64 + j2 * 16 + nlo;
                    y[(size_t)dr * 1024 + col] = acc[i][j2][rr] + bv[j2];
                }
            }
        }
    }
}

// ---------- host ----------
extern "C" void kernel_launch(void* const* d_in, const int* in_sizes, int n_in,
                              void* d_out, int out_size, void* d_ws, size_t ws_size,
                              hipStream_t stream)
{
    const float* x      = (const float*)d_in[0];
    const float* Wkv    = (const float*)d_in[1];
    const float* bkv    = (const float*)d_in[2];
    const float* Wq     = (const float*)d_in[3];
    const float* bq     = (const float*)d_in[4];
    const float* Wp     = (const float*)d_in[5];
    const float* bp     = (const float*)d_in[6];
    const float* buffer = (const float*)d_in[7];
    const int*   sl     = (const int*)d_in[8];

    int E  = in_sizes[6];          // 1024
    int Kc = in_sizes[4];          // 512
    int T  = in_sizes[0] / E;      // 4096
    int Bn = in_sizes[8];          // 8
    int EK = E + Kc;               // 1536
    int NKVQ = EK + Kc;            // 2048
    int MAXL = out_size / (Bn * E);
    int TEXT = T + 31 * Bn;        // 4344 ext rows

    size_t nX = (size_t)T * E, nWkv = (size_t)EK * E, nWq = (size_t)Kc * E;
    size_t nWp = (size_t)E * E, nBuf = (size_t)in_sizes[7];

    short* xb    = (short*)d_ws;
    short* wkvqb = xb + nX;                 // [2048,1024] merged weights
    short* wpb   = wkvqb + nWkv + nWq;
    short* qbuf  = wpb + nWp;               // [T,512]
    short* extb  = qbuf + (size_t)T * Kc;   // [TEXT,1536]
    short* ob    = extb + (size_t)TEXT * EK;
    int*   extrowp = (int*)(ob + (size_t)T * E);
    int*   destrow = extrowp + T;
    float* biascat = (float*)(destrow + T);
    int*   barp    = (int*)(biascat + NKVQ);

    float* y = (float*)d_out;

    long n0 = (long)nX, n1 = n0 + (long)nWkv, n2 = n1 + (long)nWq;
    long n3 = n2 + (long)nWp, n4 = n3 + (long)nBuf;

    hipMemsetAsync(barp, 0, 2 * sizeof(int), stream);
    fused_kernel<<<512, 256, 0, stream>>>(
        x, Wkv, Wq, Wp, buffer, sl, bkv, bq, bp,
        xb, wkvqb, wpb, qbuf, extb, ob,
        extrowp, destrow, biascat, y, barp, barp + 1,
        n0, n1, n2, n3, n4, T, Bn, MAXL, EK, NKVQ);
}

// Round 10
// 252.190 us; speedup vs baseline: 1.0872x; 1.0872x over previous
//
#include <hip/hip_runtime.h>

typedef __attribute__((ext_vector_type(8))) short short8v;
typedef __attribute__((ext_vector_type(4))) float f32x4;

// ---------- helpers ----------
__device__ inline unsigned short f2b(float f) {
    unsigned u = __builtin_bit_cast(unsigned, f);
    unsigned r = u + 0x7fffu + ((u >> 16) & 1u);
    return (unsigned short)(r >> 16);
}
__device__ inline void gload16(const void* g, void* l) {
    __builtin_amdgcn_global_load_lds(
        (const __attribute__((address_space(1))) void*)g,
        (__attribute__((address_space(3))) void*)l, 16, 0, 0);
}

// device-scope grid barrier. Key fix vs R9: the wait loop polls with RELAXED
// atomic loads (no per-iteration cache invalidation); a single ACQUIRE load
// after the loop synchronizes-with the releasing increment. Per-object
// coherence makes the relaxed gen reads monotone, so the exit condition is
// exactly as safe as the acquire-polling version.
__device__ __forceinline__ void gsync(int* cnt, int* gen) {
    __syncthreads();
    if (threadIdx.x == 0) {
        int g = __hip_atomic_load(gen, __ATOMIC_RELAXED, __HIP_MEMORY_SCOPE_AGENT);
        __threadfence();
        int a = __hip_atomic_fetch_add(cnt, 1, __ATOMIC_ACQ_REL, __HIP_MEMORY_SCOPE_AGENT);
        if (a == (int)gridDim.x - 1) {
            __hip_atomic_store(cnt, 0, __ATOMIC_RELAXED, __HIP_MEMORY_SCOPE_AGENT);
            __hip_atomic_fetch_add(gen, 1, __ATOMIC_RELEASE, __HIP_MEMORY_SCOPE_AGENT);
        } else {
            while (__hip_atomic_load(gen, __ATOMIC_RELAXED, __HIP_MEMORY_SCOPE_AGENT) == g)
                __builtin_amdgcn_s_sleep(8);
            (void)__hip_atomic_load(gen, __ATOMIC_ACQUIRE, __HIP_MEMORY_SCOPE_AGENT);
        }
    }
    __syncthreads();
}

__global__ __launch_bounds__(256, 3)
void fused_kernel(const float* __restrict__ x, const float* __restrict__ wkv,
                  const float* __restrict__ wq, const float* __restrict__ wp,
                  const float* __restrict__ buf, const int* __restrict__ sl,
                  const float* __restrict__ bkv, const float* __restrict__ bq,
                  const float* __restrict__ bp,
                  short* __restrict__ xb, short* __restrict__ wkvqb,
                  short* __restrict__ wpb, short* __restrict__ qbuf,
                  short* __restrict__ extb, short* __restrict__ ob,
                  int* __restrict__ extrow, int* __restrict__ destrow,
                  float* __restrict__ biascat, float* __restrict__ y,
                  int* bar_cnt, int* bar_gen,
                  long n0, long n1, long n2, long n3, long n4,
                  int T, int Bn, int MAXL, int EK, int NKVQ)
{
    __shared__ __align__(16) char pool[50432];
    const int tid = threadIdx.x;
    const int lane = tid & 63, wid = tid >> 6;
    const int nlo = lane & 15, g4 = lane >> 4;

    // ================= phase 0: prep + padzero =================
    {
        long gs = (long)gridDim.x * blockDim.x;
        long gid0 = (long)blockIdx.x * blockDim.x + tid;
        for (long e = gid0 * 8; e < n4; e += gs * 8) {
            if (e < n3) {
                const float* s; long off;
                if (e < n0)      { s = x;   off = e; }
                else if (e < n1) { s = wkv; off = e - n0; }
                else if (e < n2) { s = wq;  off = e - n1; }
                else             { s = wp;  off = e - n2; }
                float4 a = *(const float4*)(s + off);
                float4 b = *(const float4*)(s + off + 4);
                short8v o;
                o[0] = (short)f2b(a.x); o[1] = (short)f2b(a.y);
                o[2] = (short)f2b(a.z); o[3] = (short)f2b(a.w);
                o[4] = (short)f2b(b.x); o[5] = (short)f2b(b.y);
                o[6] = (short)f2b(b.z); o[7] = (short)f2b(b.w);
                *(short8v*)(xb + e) = o;
            } else {
                long off = e - n3;
                int brow = (int)(off / EK);
                int bcol = (int)(off % EK);
                float4 a = *(const float4*)(buf + off);
                float4 b = *(const float4*)(buf + off + 4);
                short8v o;
                o[0] = (short)f2b(a.x); o[1] = (short)f2b(a.y);
                o[2] = (short)f2b(a.z); o[3] = (short)f2b(a.w);
                o[4] = (short)f2b(b.x); o[5] = (short)f2b(b.y);
                o[6] = (short)f2b(b.z); o[7] = (short)f2b(b.w);
                int start = 0;
                for (int s8 = 0; s8 < Bn; ++s8) {
                    int dr = 31 * s8 + start + brow;
                    *(short8v*)&extb[(size_t)dr * EK + bcol] = o;
                    start += sl[s8];
                }
            }
        }
        if (gid0 < T) {
            int start = 0, seg = 0, jloc = 0;
            for (int i = 0; i < Bn; ++i) {
                int len = sl[i];
                if (gid0 >= start && gid0 < start + len) { seg = i; jloc = (int)gid0 - start; }
                start += len;
            }
            destrow[gid0] = seg * MAXL + jloc;
            extrow[gid0]  = 31 * (seg + 1) + (int)gid0;
        }
        if (gid0 < NKVQ)
            biascat[gid0] = (gid0 < EK) ? bkv[gid0] : bq[gid0 - EK];
        // padzero: one y row per block-iteration
        for (int row = blockIdx.x; row < Bn * MAXL; row += gridDim.x) {
            int seg = row / MAXL, pos = row - seg * MAXL;
            if (pos >= sl[seg]) {
                float4 z = {0.f, 0.f, 0.f, 0.f};
                *(float4*)&y[(size_t)row * 1024 + tid * 4] = z;
            }
        }
    }
    gsync(bar_cnt, bar_gen);

    // ================= phase 1: gemm1  [T,1024]@[2048,1024]^T =================
    {
        short* lA = (short*)pool;              // [2][128*32]
        short* lB = (short*)(pool + 16384);    // [2][128*32]
        int bid = (blockIdx.x & 7) * 64 + (blockIdx.x >> 3);
        int m0 = (bid >> 4) << 7, nn0 = (bid & 15) << 7;
        int wm = wid >> 1, wn = wid & 1;
        f32x4 acc[4][4];
        #pragma unroll
        for (int i = 0; i < 4; ++i)
            #pragma unroll
            for (int j2 = 0; j2 < 4; ++j2)
                acc[i][j2] = (f32x4)(0.f);
        int srow = tid >> 2, scol = (tid & 3) * 8;
        const short* ga = xb + (size_t)(m0 + srow) * 1024 + scol;
        const short* gb = wkvqb + (size_t)(nn0 + srow) * 1024 + scol;
        auto stage1 = [&](int b2, int k0) {
            gload16(ga + k0,           &lA[b2 * 4096 + tid * 8]);
            gload16(ga + 65536 + k0,   &lA[b2 * 4096 + 2048 + tid * 8]);
            gload16(gb + k0,           &lB[b2 * 4096 + tid * 8]);
            gload16(gb + 65536 + k0,   &lB[b2 * 4096 + 2048 + tid * 8]);
        };
        stage1(0, 0);
        for (int t = 0; t < 32; ++t) {
            __syncthreads();
            if (t + 1 < 32) stage1((t + 1) & 1, (t + 1) << 5);
            int cb = t & 1;
            short8v af[4], bf[4];
            #pragma unroll
            for (int f = 0; f < 4; ++f)
                af[f] = *(const short8v*)&lA[cb * 4096 + (wm * 64 + f * 16 + nlo) * 32 + g4 * 8];
            #pragma unroll
            for (int f = 0; f < 4; ++f)
                bf[f] = *(const short8v*)&lB[cb * 4096 + (wn * 64 + f * 16 + nlo) * 32 + g4 * 8];
            #pragma unroll
            for (int i = 0; i < 4; ++i)
                #pragma unroll
                for (int j2 = 0; j2 < 4; ++j2)
                    acc[i][j2] = __builtin_amdgcn_mfma_f32_16x16x32_bf16(
                        af[i], bf[j2], acc[i][j2], 0, 0, 0);
        }
        int cr = g4 * 4;
        float bv[4];
        #pragma unroll
        for (int j2 = 0; j2 < 4; ++j2)
            bv[j2] = biascat[nn0 + wn * 64 + j2 * 16 + nlo];
        #pragma unroll
        for (int i = 0; i < 4; ++i) {
            #pragma unroll
            for (int rr = 0; rr < 4; ++rr) {
                int row = m0 + wm * 64 + i * 16 + cr + rr;
                int dr = extrow[row];
                #pragma unroll
                for (int j2 = 0; j2 < 4; ++j2) {
                    int col = nn0 + wn * 64 + j2 * 16 + nlo;
                    float v = acc[i][j2][rr] + bv[j2];
                    if (col < 1536)
                        extb[(size_t)dr * 1536 + col] = (short)f2b(v);
                    else
                        qbuf[(size_t)row * 512 + (col - 1536)] = (short)f2b(v);
                }
            }
        }
    }
    gsync(bar_cnt, bar_gen);

    // ================= phase 2: attention (2 tiles per block) =================
    {
        short* lK = (short*)pool;               // 4*48*40
        short* lV = (short*)(pool + 15360);     // 4*48*66
        short* ps = (short*)(pool + 40704);     // 4*16*76
        int sb = (blockIdx.x & 7) * 64 + (blockIdx.x >> 3);
        // zero ps cols 48..63 once (never rewritten)
        if (tid < 128) {
            int hd = tid >> 5, rw = (tid >> 1) & 15, hf = tid & 1;
            uint4 z = {0u, 0u, 0u, 0u};
            *(uint4*)&ps[hd * 1216 + rw * 76 + 48 + hf * 8] = z;
        }
        #pragma unroll 1
        for (int it = 0; it < 2; ++it) {
            int tile = sb * 2 + it;
            int tg = tile >> 2, hg = tile & 3;
            int t0 = tg << 4, h0 = hg << 2;
            int r0 = extrow[t0] - 31;
            if (it) __syncthreads();   // prev PV reads done before restaging
            #pragma unroll
            for (int p = 0; p < 3; ++p) {
                int q = p * 256 + tid;
                int hd = q / 192, rem = q - hd * 192;
                int rr = rem >> 2, cc = rem & 3;
                int sr = r0 + (rr < 47 ? rr : 46);
                *(short8v*)&lK[hd * 1920 + rr * 40 + cc * 8] =
                    *(const short8v*)&extb[(size_t)sr * 1536 + (h0 + hd) * 32 + cc * 8];
            }
            #pragma unroll
            for (int p = 0; p < 6; ++p) {
                int q = p * 256 + tid;
                int hd = q / 384, rem = q - hd * 384;
                int rr = rem >> 3, cc = rem & 7;
                int sr = r0 + (rr < 47 ? rr : 46);
                *(short8v*)&lV[hd * 3168 + rr * 66 + cc * 8] =
                    *(const short8v*)&extb[(size_t)sr * 1536 + 512 + (h0 + hd) * 64 + cc * 8];
            }
            int h = h0 + wid;
            short8v aq = *(const short8v*)&qbuf[(size_t)(t0 + nlo) * 512 + h * 32 + g4 * 8];
            __syncthreads();
            f32x4 sg[3];
            #pragma unroll
            for (int g = 0; g < 3; ++g) {
                short8v bk = *(const short8v*)&lK[wid * 1920 + (g * 16 + nlo) * 40 + g4 * 8];
                f32x4 z = (f32x4)(0.f);
                sg[g] = __builtin_amdgcn_mfma_f32_16x16x32_bf16(aq, bk, z, 0, 0, 0);
            }
            const float scale = 0.17677669529663687f;
            #pragma unroll
            for (int r = 0; r < 4; ++r) {
                int tk = g4 * 4 + r;
                bool v0 = (nlo >= tk);
                bool v2 = (nlo < tk);
                float s0 = v0 ? sg[0][r] * scale : -1e30f;
                float s1 = sg[1][r] * scale;
                float s2 = v2 ? sg[2][r] * scale : -1e30f;
                float m = fmaxf(fmaxf(s0, s1), s2);
                m = fmaxf(m, __shfl_xor(m, 1, 64));
                m = fmaxf(m, __shfl_xor(m, 2, 64));
                m = fmaxf(m, __shfl_xor(m, 4, 64));
                m = fmaxf(m, __shfl_xor(m, 8, 64));
                float p0 = v0 ? __expf(s0 - m) : 0.f;
                float p1 = __expf(s1 - m);
                float p2 = v2 ? __expf(s2 - m) : 0.f;
                float sm = p0 + p1 + p2;
                sm += __shfl_xor(sm, 1, 64);
                sm += __shfl_xor(sm, 2, 64);
                sm += __shfl_xor(sm, 4, 64);
                sm += __shfl_xor(sm, 8, 64);
                float inv = 1.f / sm;
                short* pr = &ps[wid * 1216 + tk * 76];
                pr[nlo]      = (short)f2b(p0 * inv);
                pr[16 + nlo] = (short)f2b(p1 * inv);
                pr[32 + nlo] = (short)f2b(p2 * inv);
            }
            short8v pa0 = *(const short8v*)&ps[wid * 1216 + nlo * 76 + g4 * 8];
            short8v pa1 = *(const short8v*)&ps[wid * 1216 + nlo * 76 + 32 + g4 * 8];
            #pragma unroll
            for (int dvt = 0; dvt < 4; ++dvt) {
                f32x4 acc = (f32x4)(0.f);
                short8v b0, b1;
                #pragma unroll
                for (int j = 0; j < 8; ++j)
                    b0[j] = lV[wid * 3168 + (g4 * 8 + j) * 66 + dvt * 16 + nlo];
                acc = __builtin_amdgcn_mfma_f32_16x16x32_bf16(pa0, b0, acc, 0, 0, 0);
                #pragma unroll
                for (int j = 0; j < 8; ++j) {
                    int lr = 32 + g4 * 8 + j;
                    int rowc = lr < 47 ? lr : 47;
                    b1[j] = lV[wid * 3168 + rowc * 66 + dvt * 16 + nlo];
                }
                acc = __builtin_amdgcn_mfma_f32_16x16x32_bf16(pa1, b1, acc, 0, 0, 0);
                #pragma unroll
                for (int r = 0; r < 4; ++r) {
                    int t = t0 + g4 * 4 + r;
                    ob[(size_t)t * 1024 + h * 64 + dvt * 16 + nlo] = (short)f2b(acc[r]);
                }
            }
        }
    }
    gsync(bar_cnt, bar_gen);

    // ================= phase 3: gemm2  64x128 tiles, [T,1024]@[1024,1024]^T ====
    {
        short* lA = (short*)pool;              // [2][64*32]
        short* lB = (short*)(pool + 8192);     // [2][128*32]
        int bid = (blockIdx.x & 7) * 64 + (blockIdx.x >> 3);
        int m0 = (bid >> 3) * 64, nn0 = (bid & 7) << 7;
        int wm = wid >> 1, wn = wid & 1;
        f32x4 acc[2][4];
        #pragma unroll
        for (int i = 0; i < 2; ++i)
            #pragma unroll
            for (int j2 = 0; j2 < 4; ++j2)
                acc[i][j2] = (f32x4)(0.f);
        int srow = tid >> 2, scol = (tid & 3) * 8;
        const short* ga = ob + (size_t)(m0 + srow) * 1024 + scol;
        const short* gb = wpb + (size_t)(nn0 + srow) * 1024 + scol;
        auto stage2 = [&](int b2, int k0) {
            if (srow < 64)
                gload16(ga + k0, &lA[b2 * 2048 + tid * 8]);
            gload16(gb + k0,         &lB[b2 * 4096 + tid * 8]);
            gload16(gb + 65536 + k0, &lB[b2 * 4096 + 2048 + tid * 8]);
        };
        stage2(0, 0);
        for (int t = 0; t < 32; ++t) {
            __syncthreads();
            if (t + 1 < 32) stage2((t + 1) & 1, (t + 1) << 5);
            int cb = t & 1;
            short8v af[2], bf[4];
            #pragma unroll
            for (int f = 0; f < 2; ++f)
                af[f] = *(const short8v*)&lA[cb * 2048 + (wm * 32 + f * 16 + nlo) * 32 + g4 * 8];
            #pragma unroll
            for (int f = 0; f < 4; ++f)
                bf[f] = *(const short8v*)&lB[cb * 4096 + (wn * 64 + f * 16 + nlo) * 32 + g4 * 8];
            #pragma unroll
            for (int i = 0; i < 2; ++i)
                #pragma unroll
                for (int j2 = 0; j2 < 4; ++j2)
                    acc[i][j2] = __builtin_amdgcn_mfma_f32_16x16x32_bf16(
                        af[i], bf[j2], acc[i][j2], 0, 0, 0);
        }
        int cr = g4 * 4;
        float bv[4];
        #pragma unroll
        for (int j2 = 0; j2 < 4; ++j2)
            bv[j2] = bp[nn0 + wn * 64 + j2 * 16 + nlo];
        #pragma unroll
        for (int i = 0; i < 2; ++i) {
            #pragma unroll
            for (int rr = 0; rr < 4; ++rr) {
                int row = m0 + wm * 32 + i * 16 + cr + rr;
                int dr = destrow[row];
                #pragma unroll
                for (int j2 = 0; j2 < 4; ++j2) {
                    int col = nn0 + wn * 64 + j2 * 16 + nlo;
                    y[(size_t)dr * 1024 + col] = acc[i][j2][rr] + bv[j2];
                }
            }
        }
    }
}

// ---------- host ----------
extern "C" void kernel_launch(void* const* d_in, const int* in_sizes, int n_in,
                              void* d_out, int out_size, void* d_ws, size_t ws_size,
                              hipStream_t stream)
{
    const float* x      = (const float*)d_in[0];
    const float* Wkv    = (const float*)d_in[1];
    const float* bkv    = (const float*)d_in[2];
    const float* Wq     = (const float*)d_in[3];
    const float* bq     = (const float*)d_in[4];
    const float* Wp     = (const float*)d_in[5];
    const float* bp     = (const float*)d_in[6];
    const float* buffer = (const float*)d_in[7];
    const int*   sl     = (const int*)d_in[8];

    int E  = in_sizes[6];          // 1024
    int Kc = in_sizes[4];          // 512
    int T  = in_sizes[0] / E;      // 4096
    int Bn = in_sizes[8];          // 8
    int EK = E + Kc;               // 1536
    int NKVQ = EK + Kc;            // 2048
    int MAXL = out_size / (Bn * E);
    int TEXT = T + 31 * Bn;        // 4344 ext rows

    size_t nX = (size_t)T * E, nWkv = (size_t)EK * E, nWq = (size_t)Kc * E;
    size_t nWp = (size_t)E * E, nBuf = (size_t)in_sizes[7];

    short* xb    = (short*)d_ws;
    short* wkvqb = xb + nX;                 // [2048,1024] merged weights
    short* wpb   = wkvqb + nWkv + nWq;
    short* qbuf  = wpb + nWp;               // [T,512]
    short* extb  = qbuf + (size_t)T * Kc;   // [TEXT,1536]
    short* ob    = extb + (size_t)TEXT * EK;
    int*   extrowp = (int*)(ob + (size_t)T * E);
    int*   destrow = extrowp + T;
    float* biascat = (float*)(destrow + T);
    int*   barp    = (int*)(biascat + NKVQ);

    float* y = (float*)d_out;

    long n0 = (long)nX, n1 = n0 + (long)nWkv, n2 = n1 + (long)nWq;
    long n3 = n2 + (long)nWp, n4 = n3 + (long)nBuf;

    hipMemsetAsync(barp, 0, 2 * sizeof(int), stream);
    fused_kernel<<<512, 256, 0, stream>>>(
        x, Wkv, Wq, Wp, buffer, sl, bkv, bq, bp,
        xb, wkvqb, wpb, qbuf, extb, ob,
        extrowp, destrow, biascat, y, barp, barp + 1,
        n0, n1, n2, n3, n4, T, Bn, MAXL, EK, NKVQ);
}

// Round 11
// 72.987 us; speedup vs baseline: 3.7566x; 3.4553x over previous
//
#include <hip/hip_runtime.h>

typedef __attribute__((ext_vector_type(8))) short short8v;
typedef __attribute__((ext_vector_type(4))) float f32x4;

// ---------- helpers ----------
__device__ inline unsigned short f2b(float f) {
    unsigned u = __builtin_bit_cast(unsigned, f);
    unsigned r = u + 0x7fffu + ((u >> 16) & 1u);
    return (unsigned short)(r >> 16);
}
__device__ inline void gload16(const void* g, void* l) {
    __builtin_amdgcn_global_load_lds(
        (const __attribute__((address_space(1))) void*)g,
        (__attribute__((address_space(3))) void*)l, 16, 0, 0);
}

// ---------- prep: f32->bf16 conversion + ext prefixes + row maps + padzero ----------
__global__ __launch_bounds__(256)
void prep_kernel(const float* __restrict__ x, const float* __restrict__ wkv,
                 const float* __restrict__ wq, const float* __restrict__ wp,
                 const float* __restrict__ buf, const int* __restrict__ sl,
                 const float* __restrict__ bkv, const float* __restrict__ bq,
                 short* __restrict__ dst, short* __restrict__ ext,
                 int* __restrict__ extrow, int* __restrict__ destrow,
                 float* __restrict__ biascat, float* __restrict__ y,
                 long n0, long n1, long n2, long n3, long n4,
                 int T, int Bn, int MAXL, int EK, int NKVQ)
{
    long gid = (long)blockIdx.x * blockDim.x + threadIdx.x;
    long e = gid * 8;
    if (e < n3) {
        const float* s; long off;
        if (e < n0)      { s = x;   off = e; }
        else if (e < n1) { s = wkv; off = e - n0; }
        else if (e < n2) { s = wq;  off = e - n1; }
        else             { s = wp;  off = e - n2; }
        float4 a = *(const float4*)(s + off);
        float4 b = *(const float4*)(s + off + 4);
        short8v o;
        o[0] = (short)f2b(a.x); o[1] = (short)f2b(a.y);
        o[2] = (short)f2b(a.z); o[3] = (short)f2b(a.w);
        o[4] = (short)f2b(b.x); o[5] = (short)f2b(b.y);
        o[6] = (short)f2b(b.z); o[7] = (short)f2b(b.w);
        *(short8v*)(dst + e) = o;
    } else if (e < n4) {
        // learned buffer rows -> 31-row prefix of every segment in ext
        long off = e - n3;
        int brow = (int)(off / EK);
        int bcol = (int)(off % EK);
        float4 a = *(const float4*)(buf + off);
        float4 b = *(const float4*)(buf + off + 4);
        short8v o;
        o[0] = (short)f2b(a.x); o[1] = (short)f2b(a.y);
        o[2] = (short)f2b(a.z); o[3] = (short)f2b(a.w);
        o[4] = (short)f2b(b.x); o[5] = (short)f2b(b.y);
        o[6] = (short)f2b(b.z); o[7] = (short)f2b(b.w);
        int start = 0;
        for (int s8 = 0; s8 < 8; ++s8) {
            int dr = 31 * s8 + start + brow;
            *(short8v*)&ext[(size_t)dr * EK + bcol] = o;
            start += sl[s8];
        }
    }
    if (gid < T) {
        int start = 0, seg = 0, jloc = 0;
        for (int i = 0; i < Bn; ++i) {
            int len = sl[i];
            if (gid >= start && gid < start + len) { seg = i; jloc = (int)gid - start; }
            start += len;
        }
        destrow[gid] = seg * MAXL + jloc;
        extrow[gid]  = 31 * (seg + 1) + (int)gid;
    }
    if (gid < NKVQ) {
        biascat[gid] = (gid < EK) ? bkv[gid] : bq[gid - EK];
    }
    // padzero: one y row per block (grid sized to Bn*MAXL)
    int row = blockIdx.x;
    if (row < Bn * MAXL) {
        int seg = row / MAXL, pos = row - seg * MAXL;
        if (pos >= sl[seg]) {
            float4 z = {0.f, 0.f, 0.f, 0.f};
            *(float4*)&y[(size_t)row * 1024 + threadIdx.x * 4] = z;
        }
    }
}

// ---------- bf16 GEMM, 2-phase double-buffered, 128x128 (R6 structure) ----------
// MODE 0: split write: col<1536 -> bf16 ext[rowmap[row]][col]; else q[row][col-1536]
template<int MODE>
__global__ __launch_bounds__(256)
void gemm_bt(const short* __restrict__ A, const short* __restrict__ Bm,
             const float* __restrict__ bias,
             short* __restrict__ C0, short* __restrict__ C1,
             float* __restrict__ Cf, const int* __restrict__ rowmap,
             int M, int N, int Kd)
{
    __shared__ short lA[2][128 * 32];
    __shared__ short lB[2][128 * 32];
    int nb = N >> 7;
    int bid0 = blockIdx.x;
    int bid = (bid0 & 7) * ((int)gridDim.x >> 3) + (bid0 >> 3);
    int m0 = (bid / nb) << 7, n0 = (bid % nb) << 7;
    int tid = threadIdx.x;
    int lane = tid & 63, wid = tid >> 6;
    int wm = wid >> 1, wn = wid & 1;
    f32x4 acc[4][4];
    #pragma unroll
    for (int i = 0; i < 4; ++i)
        #pragma unroll
        for (int j2 = 0; j2 < 4; ++j2)
            acc[i][j2] = (f32x4)(0.f);

    const int srow = tid >> 2;
    const int scol = (tid & 3) * 8;
    const short* ga = A + (size_t)(m0 + srow) * Kd + scol;
    const short* gb = Bm + (size_t)(n0 + srow) * Kd + scol;

    auto stage = [&](int bf2, int k0) {
        gload16(ga + k0, &lA[bf2][tid * 8]);
        gload16(ga + (size_t)64 * Kd + k0, &lA[bf2][64 * 32 + tid * 8]);
        gload16(gb + k0, &lB[bf2][tid * 8]);
        gload16(gb + (size_t)64 * Kd + k0, &lB[bf2][64 * 32 + tid * 8]);
    };

    int r = lane & 15, kc = (lane >> 4) * 8;
    int nk = Kd >> 5;

    stage(0, 0);
    for (int t = 0; t < nk; ++t) {
        __syncthreads();
        if (t + 1 < nk) stage((t + 1) & 1, (t + 1) << 5);
        int cb = t & 1;
        short8v af[4], bf[4];
        #pragma unroll
        for (int f = 0; f < 4; ++f)
            af[f] = *(const short8v*)&lA[cb][(wm * 64 + f * 16 + r) * 32 + kc];
        #pragma unroll
        for (int f = 0; f < 4; ++f)
            bf[f] = *(const short8v*)&lB[cb][(wn * 64 + f * 16 + r) * 32 + kc];
        #pragma unroll
        for (int i = 0; i < 4; ++i)
            #pragma unroll
            for (int j2 = 0; j2 < 4; ++j2)
                acc[i][j2] = __builtin_amdgcn_mfma_f32_16x16x32_bf16(
                    af[i], bf[j2], acc[i][j2], 0, 0, 0);
    }

    int cr = (lane >> 4) * 4;
    int cc = lane & 15;
    float bv[4];
    #pragma unroll
    for (int j2 = 0; j2 < 4; ++j2)
        bv[j2] = bias[n0 + wn * 64 + j2 * 16 + cc];
    #pragma unroll
    for (int i = 0; i < 4; ++i) {
        #pragma unroll
        for (int rr = 0; rr < 4; ++rr) {
            int row = m0 + wm * 64 + i * 16 + cr + rr;
            int dr = rowmap[row];
            #pragma unroll
            for (int j2 = 0; j2 < 4; ++j2) {
                int col = n0 + wn * 64 + j2 * 16 + cc;
                float v = acc[i][j2][rr] + bv[j2];
                if (MODE == 0) {
                    if (col < 1536)
                        C0[(size_t)dr * 1536 + col] = (short)f2b(v);
                    else
                        C1[(size_t)row * 512 + (col - 1536)] = (short)f2b(v);
                } else {
                    Cf[(size_t)dr * N + col] = v;
                }
            }
        }
    }
}

// ---------- gemm2: 64x128 tile, 2-phase dbuf, f32 scatter epilogue ----------
// grid = (M/64)*(N/128) = 512 blocks -> 2 blocks/CU.
__global__ __launch_bounds__(256)
void gemm64(const short* __restrict__ A, const short* __restrict__ Bm,
            const float* __restrict__ bias, float* __restrict__ Cf,
            const int* __restrict__ rowmap, int M, int N, int Kd)
{
    __shared__ short lA[2][64 * 32];
    __shared__ short lB[2][128 * 32];
    int nb = N >> 7;
    int bid0 = blockIdx.x;
    int bid = (bid0 & 7) * ((int)gridDim.x >> 3) + (bid0 >> 3);
    int m0 = (bid / nb) << 6, n0 = (bid % nb) << 7;
    int tid = threadIdx.x;
    int lane = tid & 63, wid = tid >> 6;
    int wm = wid >> 1, wn = wid & 1;          // 2(M) x 2(N)
    int nlo = lane & 15, g4 = lane >> 4;

    f32x4 acc[2][4];
    #pragma unroll
    for (int i = 0; i < 2; ++i)
        #pragma unroll
        for (int j2 = 0; j2 < 4; ++j2)
            acc[i][j2] = (f32x4)(0.f);

    const int srow = tid >> 2;          // 0..63
    const int scol = (tid & 3) * 8;
    const short* ga = A + (size_t)(m0 + srow) * Kd + scol;
    const short* gb = Bm + (size_t)(n0 + srow) * Kd + scol;

    auto stage = [&](int bf2, int k0) {
        gload16(ga + k0, &lA[bf2][tid * 8]);
        gload16(gb + k0, &lB[bf2][tid * 8]);
        gload16(gb + (size_t)64 * Kd + k0, &lB[bf2][64 * 32 + tid * 8]);
    };

    int nk = Kd >> 5;
    stage(0, 0);
    for (int t = 0; t < nk; ++t) {
        __syncthreads();
        if (t + 1 < nk) stage((t + 1) & 1, (t + 1) << 5);
        int cb = t & 1;
        short8v af[2], bf[4];
        #pragma unroll
        for (int f = 0; f < 2; ++f)
            af[f] = *(const short8v*)&lA[cb][(wm * 32 + f * 16 + nlo) * 32 + g4 * 8];
        #pragma unroll
        for (int f = 0; f < 4; ++f)
            bf[f] = *(const short8v*)&lB[cb][(wn * 64 + f * 16 + nlo) * 32 + g4 * 8];
        #pragma unroll
        for (int i = 0; i < 2; ++i)
            #pragma unroll
            for (int j2 = 0; j2 < 4; ++j2)
                acc[i][j2] = __builtin_amdgcn_mfma_f32_16x16x32_bf16(
                    af[i], bf[j2], acc[i][j2], 0, 0, 0);
    }

    int cr = g4 * 4;
    float bv[4];
    #pragma unroll
    for (int j2 = 0; j2 < 4; ++j2)
        bv[j2] = bias[n0 + wn * 64 + j2 * 16 + nlo];
    #pragma unroll
    for (int i = 0; i < 2; ++i) {
        #pragma unroll
        for (int rr = 0; rr < 4; ++rr) {
            int row = m0 + wm * 32 + i * 16 + cr + rr;
            int dr = rowmap[row];
            #pragma unroll
            for (int j2 = 0; j2 < 4; ++j2) {
                int col = n0 + wn * 64 + j2 * 16 + nlo;
                Cf[(size_t)dr * N + col] = acc[i][j2][rr] + bv[j2];
            }
        }
    }
}

// ---------- windowed attention v6: MFMA ----------
__global__ __launch_bounds__(256)
void attn6_kernel(const short* __restrict__ ext, const short* __restrict__ qb,
                  const int* __restrict__ extrow, short* __restrict__ o)
{
    __shared__ short lK[4 * 48 * 40];   // [head][row<48][40]  (pad 32->40)
    __shared__ short lV[4 * 48 * 66];   // [head][row<48][66]  (pad 64->66)
    __shared__ short ps[4 * 16 * 76];   // [head][ti][76] bf16 P (pad 64->76)

    int bid = blockIdx.x;
    int swz = (bid & 7) * (gridDim.x >> 3) + (bid >> 3);  // XCD-contiguous
    int tg = swz >> 2, hg = swz & 3;
    int t0 = tg << 4, h0 = hg << 2;
    int r0 = extrow[t0] - 31;
    int tid = threadIdx.x;
    int wv = tid >> 6, lane = tid & 63;

    #pragma unroll
    for (int p = 0; p < 3; ++p) {
        int q = p * 256 + tid;
        int hd = q / 192, rem = q - hd * 192;
        int rr = rem >> 2, cc = rem & 3;
        int sr = r0 + (rr < 47 ? rr : 46);
        *(short8v*)&lK[hd * 1920 + rr * 40 + cc * 8] =
            *(const short8v*)&ext[(size_t)sr * 1536 + (h0 + hd) * 32 + cc * 8];
    }
    #pragma unroll
    for (int p = 0; p < 6; ++p) {
        int q = p * 256 + tid;
        int hd = q / 384, rem = q - hd * 384;
        int rr = rem >> 3, cc = rem & 7;
        int sr = r0 + (rr < 47 ? rr : 46);
        *(short8v*)&lV[hd * 3168 + rr * 66 + cc * 8] =
            *(const short8v*)&ext[(size_t)sr * 1536 + 512 + (h0 + hd) * 64 + cc * 8];
    }
    if (tid < 128) {
        int hd = tid >> 5, row = (tid >> 1) & 15, hf = tid & 1;
        uint4 z = {0u, 0u, 0u, 0u};
        *(uint4*)&ps[hd * 1216 + row * 76 + 48 + hf * 8] = z;
    }

    int h = h0 + wv;
    int nlo = lane & 15, g4 = lane >> 4;

    short8v aq = *(const short8v*)&qb[(size_t)(t0 + nlo) * 512 + h * 32 + g4 * 8];

    __syncthreads();

    f32x4 sg[3];
    #pragma unroll
    for (int g = 0; g < 3; ++g) {
        short8v bk = *(const short8v*)&lK[wv * 1920 + (g * 16 + nlo) * 40 + g4 * 8];
        f32x4 z = (f32x4)(0.f);
        sg[g] = __builtin_amdgcn_mfma_f32_16x16x32_bf16(aq, bk, z, 0, 0, 0);
    }

    const float scale = 0.17677669529663687f;
    #pragma unroll
    for (int r = 0; r < 4; ++r) {
        int tk = g4 * 4 + r;
        bool v0 = (nlo >= tk);
        bool v2 = (nlo < tk);
        float s0 = v0 ? sg[0][r] * scale : -1e30f;
        float s1 = sg[1][r] * scale;
        float s2 = v2 ? sg[2][r] * scale : -1e30f;
        float m = fmaxf(fmaxf(s0, s1), s2);
        m = fmaxf(m, __shfl_xor(m, 1, 64));
        m = fmaxf(m, __shfl_xor(m, 2, 64));
        m = fmaxf(m, __shfl_xor(m, 4, 64));
        m = fmaxf(m, __shfl_xor(m, 8, 64));
        float p0 = v0 ? __expf(s0 - m) : 0.f;
        float p1 = __expf(s1 - m);
        float p2 = v2 ? __expf(s2 - m) : 0.f;
        float sm = p0 + p1 + p2;
        sm += __shfl_xor(sm, 1, 64);
        sm += __shfl_xor(sm, 2, 64);
        sm += __shfl_xor(sm, 4, 64);
        sm += __shfl_xor(sm, 8, 64);
        float inv = 1.f / sm;
        short* pr = &ps[wv * 1216 + tk * 76];
        pr[nlo]      = (short)f2b(p0 * inv);
        pr[16 + nlo] = (short)f2b(p1 * inv);
        pr[32 + nlo] = (short)f2b(p2 * inv);
    }

    short8v pa0 = *(const short8v*)&ps[wv * 1216 + nlo * 76 + g4 * 8];
    short8v pa1 = *(const short8v*)&ps[wv * 1216 + nlo * 76 + 32 + g4 * 8];
    #pragma unroll
    for (int dvt = 0; dvt < 4; ++dvt) {
        f32x4 acc = (f32x4)(0.f);
        short8v b0, b1;
        #pragma unroll
        for (int j = 0; j < 8; ++j)
            b0[j] = lV[wv * 3168 + (g4 * 8 + j) * 66 + dvt * 16 + nlo];
        acc = __builtin_amdgcn_mfma_f32_16x16x32_bf16(pa0, b0, acc, 0, 0, 0);
        #pragma unroll
        for (int j = 0; j < 8; ++j) {
            int lr = 32 + g4 * 8 + j;
            int rowc = lr < 47 ? lr : 47;    // clamp; P=0 there anyway
            b1[j] = lV[wv * 3168 + rowc * 66 + dvt * 16 + nlo];
        }
        acc = __builtin_amdgcn_mfma_f32_16x16x32_bf16(pa1, b1, acc, 0, 0, 0);
        #pragma unroll
        for (int r = 0; r < 4; ++r) {
            int t = t0 + g4 * 4 + r;
            o[(size_t)t * 1024 + h * 64 + dvt * 16 + nlo] = (short)f2b(acc[r]);
        }
    }
}

// ---------- host ----------
extern "C" void kernel_launch(void* const* d_in, const int* in_sizes, int n_in,
                              void* d_out, int out_size, void* d_ws, size_t ws_size,
                              hipStream_t stream)
{
    const float* x      = (const float*)d_in[0];
    const float* Wkv    = (const float*)d_in[1];
    const float* bkv    = (const float*)d_in[2];
    const float* Wq     = (const float*)d_in[3];
    const float* bq     = (const float*)d_in[4];
    const float* Wp     = (const float*)d_in[5];
    const float* bp     = (const float*)d_in[6];
    const float* buffer = (const float*)d_in[7];
    const int*   sl     = (const int*)d_in[8];

    int E  = in_sizes[6];          // 1024
    int Kc = in_sizes[4];          // 512
    int T  = in_sizes[0] / E;      // 4096
    int Bn = in_sizes[8];          // 8
    int EK = E + Kc;               // 1536
    int NKVQ = EK + Kc;            // 2048
    int MAXL = out_size / (Bn * E);
    int TEXT = T + 31 * Bn;        // 4344 ext rows

    size_t nX = (size_t)T * E, nWkv = (size_t)EK * E, nWq = (size_t)Kc * E;
    size_t nWp = (size_t)E * E, nBuf = (size_t)in_sizes[7];

    short* xb    = (short*)d_ws;
    short* wkvqb = xb + nX;                 // [2048,1024] merged weights
    short* wpb   = wkvqb + nWkv + nWq;
    short* qbuf  = wpb + nWp;               // [T,512]
    short* extb  = qbuf + (size_t)T * Kc;   // [TEXT,1536]
    short* ob    = extb + (size_t)TEXT * EK;
    int*   extrowp = (int*)(ob + (size_t)T * E);
    int*   destrow = extrowp + T;
    float* biascat = (float*)(destrow + T);

    float* y = (float*)d_out;

    long n0 = (long)nX, n1 = n0 + (long)nWkv, n2 = n1 + (long)nWq;
    long n3 = n2 + (long)nWp, n4 = n3 + (long)nBuf;
    int prep_blocks = Bn * MAXL;   // 6144: covers both conversion and padzero
    prep_kernel<<<prep_blocks, 256, 0, stream>>>(
        x, Wkv, Wq, Wp, buffer, sl, bkv, bq, xb, extb,
        extrowp, destrow, biascat, y,
        n0, n1, n2, n3, n4, T, Bn, MAXL, EK, NKVQ);

    // merged kv+q projection; kv rows scatter into ext layout, q separate
    gemm_bt<0><<<(T / 128) * (NKVQ / 128), 256, 0, stream>>>(
        xb, wkvqb, biascat, extb, qbuf, nullptr, extrowp, T, NKVQ, E);

    attn6_kernel<<<(T / 16) * 4, 256, 0, stream>>>(extb, qbuf, extrowp, ob);

    gemm64<<<(T / 64) * (E / 128), 256, 0, stream>>>(
        ob, wpb, bp, y, destrow, T, E, E);
}

// Round 12
// 69.584 us; speedup vs baseline: 3.9403x; 1.0489x over previous
//
#include <hip/hip_runtime.h>

typedef __attribute__((ext_vector_type(8))) short short8v;
typedef __attribute__((ext_vector_type(4))) float f32x4;

// ---------- helpers ----------
__device__ inline unsigned short f2b(float f) {
    unsigned u = __builtin_bit_cast(unsigned, f);
    unsigned r = u + 0x7fffu + ((u >> 16) & 1u);
    return (unsigned short)(r >> 16);
}
__device__ inline void gload16(const void* g, void* l) {
    __builtin_amdgcn_global_load_lds(
        (const __attribute__((address_space(1))) void*)g,
        (__attribute__((address_space(3))) void*)l, 16, 0, 0);
}

// ---------- prep: f32->bf16 conversion + ext prefixes + row maps + padzero ----------
__global__ __launch_bounds__(256)
void prep_kernel(const float* __restrict__ x, const float* __restrict__ wkv,
                 const float* __restrict__ wq, const float* __restrict__ wp,
                 const float* __restrict__ buf, const int* __restrict__ sl,
                 const float* __restrict__ bkv, const float* __restrict__ bq,
                 short* __restrict__ dst, short* __restrict__ ext,
                 int* __restrict__ extrow, int* __restrict__ destrow,
                 float* __restrict__ biascat, float* __restrict__ y,
                 long n0, long n1, long n2, long n3, long n4,
                 int T, int Bn, int MAXL, int EK, int NKVQ)
{
    long gid = (long)blockIdx.x * blockDim.x + threadIdx.x;
    long e = gid * 8;
    if (e < n3) {
        const float* s; long off;
        if (e < n0)      { s = x;   off = e; }
        else if (e < n1) { s = wkv; off = e - n0; }
        else if (e < n2) { s = wq;  off = e - n1; }
        else             { s = wp;  off = e - n2; }
        float4 a = *(const float4*)(s + off);
        float4 b = *(const float4*)(s + off + 4);
        short8v o;
        o[0] = (short)f2b(a.x); o[1] = (short)f2b(a.y);
        o[2] = (short)f2b(a.z); o[3] = (short)f2b(a.w);
        o[4] = (short)f2b(b.x); o[5] = (short)f2b(b.y);
        o[6] = (short)f2b(b.z); o[7] = (short)f2b(b.w);
        *(short8v*)(dst + e) = o;
    } else if (e < n4) {
        // learned buffer rows -> 31-row prefix of every segment in ext
        long off = e - n3;
        int brow = (int)(off / EK);
        int bcol = (int)(off % EK);
        float4 a = *(const float4*)(buf + off);
        float4 b = *(const float4*)(buf + off + 4);
        short8v o;
        o[0] = (short)f2b(a.x); o[1] = (short)f2b(a.y);
        o[2] = (short)f2b(a.z); o[3] = (short)f2b(a.w);
        o[4] = (short)f2b(b.x); o[5] = (short)f2b(b.y);
        o[6] = (short)f2b(b.z); o[7] = (short)f2b(b.w);
        int start = 0;
        for (int s8 = 0; s8 < 8; ++s8) {
            int dr = 31 * s8 + start + brow;
            *(short8v*)&ext[(size_t)dr * EK + bcol] = o;
            start += sl[s8];
        }
    }
    if (gid < T) {
        int start = 0, seg = 0, jloc = 0;
        for (int i = 0; i < Bn; ++i) {
            int len = sl[i];
            if (gid >= start && gid < start + len) { seg = i; jloc = (int)gid - start; }
            start += len;
        }
        destrow[gid] = seg * MAXL + jloc;
        extrow[gid]  = 31 * (seg + 1) + (int)gid;
    }
    if (gid < NKVQ) {
        biascat[gid] = (gid < EK) ? bkv[gid] : bq[gid - EK];
    }
    // padzero: one y row per block (grid sized to Bn*MAXL)
    int row = blockIdx.x;
    if (row < Bn * MAXL) {
        int seg = row / MAXL, pos = row - seg * MAXL;
        if (pos >= sl[seg]) {
            float4 z = {0.f, 0.f, 0.f, 0.f};
            *(float4*)&y[(size_t)row * 1024 + threadIdx.x * 4] = z;
        }
    }
}

// ---------- bf16 GEMM, 64x128 tile, 2-phase dbuf, 4 waves ----------
// C[M,N] = A[M,K] @ B[N,K]^T + bias
// MODE 0: split write: col<1536 -> bf16 ext[rowmap[row]][col]; else q[row][col-1536]
// MODE 1: f32 rows scattered: y[rowmap[row]][col]
template<int MODE>
__global__ __launch_bounds__(256)
void gemm64t(const short* __restrict__ A, const short* __restrict__ Bm,
             const float* __restrict__ bias,
             short* __restrict__ C0, short* __restrict__ C1,
             float* __restrict__ Cf, const int* __restrict__ rowmap,
             int M, int N, int Kd)
{
    __shared__ short lA[2][64 * 32];
    __shared__ short lB[2][128 * 32];
    int nb = N >> 7;
    int bid0 = blockIdx.x;
    int bid = (bid0 & 7) * ((int)gridDim.x >> 3) + (bid0 >> 3);
    int m0 = (bid / nb) << 6, n0 = (bid % nb) << 7;
    int tid = threadIdx.x;
    int lane = tid & 63, wid = tid >> 6;
    int wm = wid >> 1, wn = wid & 1;          // 2(M) x 2(N) waves
    int nlo = lane & 15, g4 = lane >> 4;

    f32x4 acc[2][4];
    #pragma unroll
    for (int i = 0; i < 2; ++i)
        #pragma unroll
        for (int j2 = 0; j2 < 4; ++j2)
            acc[i][j2] = (f32x4)(0.f);

    const int srow = tid >> 2;          // 0..63
    const int scol = (tid & 3) * 8;
    const short* ga = A + (size_t)(m0 + srow) * Kd + scol;
    const short* gb = Bm + (size_t)(n0 + srow) * Kd + scol;

    auto stage = [&](int bf2, int k0) {
        gload16(ga + k0, &lA[bf2][tid * 8]);
        gload16(gb + k0, &lB[bf2][tid * 8]);
        gload16(gb + (size_t)64 * Kd + k0, &lB[bf2][64 * 32 + tid * 8]);
    };

    int nk = Kd >> 5;
    stage(0, 0);
    for (int t = 0; t < nk; ++t) {
        __syncthreads();
        if (t + 1 < nk) stage((t + 1) & 1, (t + 1) << 5);
        int cb = t & 1;
        short8v af[2], bf[4];
        #pragma unroll
        for (int f = 0; f < 2; ++f)
            af[f] = *(const short8v*)&lA[cb][(wm * 32 + f * 16 + nlo) * 32 + g4 * 8];
        #pragma unroll
        for (int f = 0; f < 4; ++f)
            bf[f] = *(const short8v*)&lB[cb][(wn * 64 + f * 16 + nlo) * 32 + g4 * 8];
        #pragma unroll
        for (int i = 0; i < 2; ++i)
            #pragma unroll
            for (int j2 = 0; j2 < 4; ++j2)
                acc[i][j2] = __builtin_amdgcn_mfma_f32_16x16x32_bf16(
                    af[i], bf[j2], acc[i][j2], 0, 0, 0);
    }

    int cr = g4 * 4;
    float bv[4];
    #pragma unroll
    for (int j2 = 0; j2 < 4; ++j2)
        bv[j2] = bias[n0 + wn * 64 + j2 * 16 + nlo];
    #pragma unroll
    for (int i = 0; i < 2; ++i) {
        #pragma unroll
        for (int rr = 0; rr < 4; ++rr) {
            int row = m0 + wm * 32 + i * 16 + cr + rr;
            int dr = rowmap[row];
            #pragma unroll
            for (int j2 = 0; j2 < 4; ++j2) {
                int col = n0 + wn * 64 + j2 * 16 + nlo;
                float v = acc[i][j2][rr] + bv[j2];
                if (MODE == 0) {
                    if (col < 1536)
                        C0[(size_t)dr * 1536 + col] = (short)f2b(v);
                    else
                        C1[(size_t)row * 512 + (col - 1536)] = (short)f2b(v);
                } else {
                    Cf[(size_t)dr * N + col] = v;
                }
            }
        }
    }
}

// ---------- windowed attention v6: MFMA ----------
__global__ __launch_bounds__(256)
void attn6_kernel(const short* __restrict__ ext, const short* __restrict__ qb,
                  const int* __restrict__ extrow, short* __restrict__ o)
{
    __shared__ short lK[4 * 48 * 40];   // [head][row<48][40]  (pad 32->40)
    __shared__ short lV[4 * 48 * 66];   // [head][row<48][66]  (pad 64->66)
    __shared__ short ps[4 * 16 * 76];   // [head][ti][76] bf16 P (pad 64->76)

    int bid = blockIdx.x;
    int swz = (bid & 7) * (gridDim.x >> 3) + (bid >> 3);  // XCD-contiguous
    int tg = swz >> 2, hg = swz & 3;
    int t0 = tg << 4, h0 = hg << 2;
    int r0 = extrow[t0] - 31;
    int tid = threadIdx.x;
    int wv = tid >> 6, lane = tid & 63;

    #pragma unroll
    for (int p = 0; p < 3; ++p) {
        int q = p * 256 + tid;
        int hd = q / 192, rem = q - hd * 192;
        int rr = rem >> 2, cc = rem & 3;
        int sr = r0 + (rr < 47 ? rr : 46);
        *(short8v*)&lK[hd * 1920 + rr * 40 + cc * 8] =
            *(const short8v*)&ext[(size_t)sr * 1536 + (h0 + hd) * 32 + cc * 8];
    }
    #pragma unroll
    for (int p = 0; p < 6; ++p) {
        int q = p * 256 + tid;
        int hd = q / 384, rem = q - hd * 384;
        int rr = rem >> 3, cc = rem & 7;
        int sr = r0 + (rr < 47 ? rr : 46);
        *(short8v*)&lV[hd * 3168 + rr * 66 + cc * 8] =
            *(const short8v*)&ext[(size_t)sr * 1536 + 512 + (h0 + hd) * 64 + cc * 8];
    }
    if (tid < 128) {
        int hd = tid >> 5, row = (tid >> 1) & 15, hf = tid & 1;
        uint4 z = {0u, 0u, 0u, 0u};
        *(uint4*)&ps[hd * 1216 + row * 76 + 48 + hf * 8] = z;
    }

    int h = h0 + wv;
    int nlo = lane & 15, g4 = lane >> 4;

    short8v aq = *(const short8v*)&qb[(size_t)(t0 + nlo) * 512 + h * 32 + g4 * 8];

    __syncthreads();

    f32x4 sg[3];
    #pragma unroll
    for (int g = 0; g < 3; ++g) {
        short8v bk = *(const short8v*)&lK[wv * 1920 + (g * 16 + nlo) * 40 + g4 * 8];
        f32x4 z = (f32x4)(0.f);
        sg[g] = __builtin_amdgcn_mfma_f32_16x16x32_bf16(aq, bk, z, 0, 0, 0);
    }

    const float scale = 0.17677669529663687f;
    #pragma unroll
    for (int r = 0; r < 4; ++r) {
        int tk = g4 * 4 + r;
        bool v0 = (nlo >= tk);
        bool v2 = (nlo < tk);
        float s0 = v0 ? sg[0][r] * scale : -1e30f;
        float s1 = sg[1][r] * scale;
        float s2 = v2 ? sg[2][r] * scale : -1e30f;
        float m = fmaxf(fmaxf(s0, s1), s2);
        m = fmaxf(m, __shfl_xor(m, 1, 64));
        m = fmaxf(m, __shfl_xor(m, 2, 64));
        m = fmaxf(m, __shfl_xor(m, 4, 64));
        m = fmaxf(m, __shfl_xor(m, 8, 64));
        float p0 = v0 ? __expf(s0 - m) : 0.f;
        float p1 = __expf(s1 - m);
        float p2 = v2 ? __expf(s2 - m) : 0.f;
        float sm = p0 + p1 + p2;
        sm += __shfl_xor(sm, 1, 64);
        sm += __shfl_xor(sm, 2, 64);
        sm += __shfl_xor(sm, 4, 64);
        sm += __shfl_xor(sm, 8, 64);
        float inv = 1.f / sm;
        short* pr = &ps[wv * 1216 + tk * 76];
        pr[nlo]      = (short)f2b(p0 * inv);
        pr[16 + nlo] = (short)f2b(p1 * inv);
        pr[32 + nlo] = (short)f2b(p2 * inv);
    }

    short8v pa0 = *(const short8v*)&ps[wv * 1216 + nlo * 76 + g4 * 8];
    short8v pa1 = *(const short8v*)&ps[wv * 1216 + nlo * 76 + 32 + g4 * 8];
    #pragma unroll
    for (int dvt = 0; dvt < 4; ++dvt) {
        f32x4 acc = (f32x4)(0.f);
        short8v b0, b1;
        #pragma unroll
        for (int j = 0; j < 8; ++j)
            b0[j] = lV[wv * 3168 + (g4 * 8 + j) * 66 + dvt * 16 + nlo];
        acc = __builtin_amdgcn_mfma_f32_16x16x32_bf16(pa0, b0, acc, 0, 0, 0);
        #pragma unroll
        for (int j = 0; j < 8; ++j) {
            int lr = 32 + g4 * 8 + j;
            int rowc = lr < 47 ? lr : 47;    // clamp; P=0 there anyway
            b1[j] = lV[wv * 3168 + rowc * 66 + dvt * 16 + nlo];
        }
        acc = __builtin_amdgcn_mfma_f32_16x16x32_bf16(pa1, b1, acc, 0, 0, 0);
        #pragma unroll
        for (int r = 0; r < 4; ++r) {
            int t = t0 + g4 * 4 + r;
            o[(size_t)t * 1024 + h * 64 + dvt * 16 + nlo] = (short)f2b(acc[r]);
        }
    }
}

// ---------- host ----------
extern "C" void kernel_launch(void* const* d_in, const int* in_sizes, int n_in,
                              void* d_out, int out_size, void* d_ws, size_t ws_size,
                              hipStream_t stream)
{
    const float* x      = (const float*)d_in[0];
    const float* Wkv    = (const float*)d_in[1];
    const float* bkv    = (const float*)d_in[2];
    const float* Wq     = (const float*)d_in[3];
    const float* bq     = (const float*)d_in[4];
    const float* Wp     = (const float*)d_in[5];
    const float* bp     = (const float*)d_in[6];
    const float* buffer = (const float*)d_in[7];
    const int*   sl     = (const int*)d_in[8];

    int E  = in_sizes[6];          // 1024
    int Kc = in_sizes[4];          // 512
    int T  = in_sizes[0] / E;      // 4096
    int Bn = in_sizes[8];          // 8
    int EK = E + Kc;               // 1536
    int NKVQ = EK + Kc;            // 2048
    int MAXL = out_size / (Bn * E);
    int TEXT = T + 31 * Bn;        // 4344 ext rows

    size_t nX = (size_t)T * E, nWkv = (size_t)EK * E, nWq = (size_t)Kc * E;
    size_t nWp = (size_t)E * E, nBuf = (size_t)in_sizes[7];

    short* xb    = (short*)d_ws;
    short* wkvqb = xb + nX;                 // [2048,1024] merged weights
    short* wpb   = wkvqb + nWkv + nWq;
    short* qbuf  = wpb + nWp;               // [T,512]
    short* extb  = qbuf + (size_t)T * Kc;   // [TEXT,1536]
    short* ob    = extb + (size_t)TEXT * EK;
    int*   extrowp = (int*)(ob + (size_t)T * E);
    int*   destrow = extrowp + T;
    float* biascat = (float*)(destrow + T);

    float* y = (float*)d_out;

    long n0 = (long)nX, n1 = n0 + (long)nWkv, n2 = n1 + (long)nWq;
    long n3 = n2 + (long)nWp, n4 = n3 + (long)nBuf;
    int prep_blocks = Bn * MAXL;   // 6144: covers both conversion and padzero
    prep_kernel<<<prep_blocks, 256, 0, stream>>>(
        x, Wkv, Wq, Wp, buffer, sl, bkv, bq, xb, extb,
        extrowp, destrow, biascat, y,
        n0, n1, n2, n3, n4, T, Bn, MAXL, EK, NKVQ);

    // merged kv+q projection; kv rows scatter into ext layout, q separate
    gemm64t<0><<<(T / 64) * (NKVQ / 128), 256, 0, stream>>>(
        xb, wkvqb, biascat, extb, qbuf, nullptr, extrowp, T, NKVQ, E);

    attn6_kernel<<<(T / 16) * 4, 256, 0, stream>>>(extb, qbuf, extrowp, ob);

    gemm64t<1><<<(T / 64) * (E / 128), 256, 0, stream>>>(
        ob, wpb, bp, nullptr, nullptr, y, destrow, T, E, E);
}